// Round 3
// baseline (146.287 us; speedup 1.0000x reference)
//
#include <hip/hip_runtime.h>

using half2v  = __attribute__((ext_vector_type(2))) _Float16;
using half4   = __attribute__((ext_vector_type(4))) _Float16;
using half8   = __attribute__((ext_vector_type(8))) _Float16;
using floatx4 = __attribute__((ext_vector_type(4))) float;

constexpr int BATCH = 2;
constexpr int NPOS  = 96 * 96;    // 9216
constexpr int NT    = NPOS / 16;  // 576 sixteen-wide i-tiles
constexpr int NST   = NPOS / 32;  // 288 thirty-two-wide j-steps

#define EXP2(x) __builtin_amdgcn_exp2f(x)
#define MFMA16(A, B, C) __builtin_amdgcn_mfma_f32_16x16x16f16(A, B, C, 0, 0, 0)
#define MFMA32(A, B, C) __builtin_amdgcn_mfma_f32_16x16x32_f16(A, B, C, 0, 0, 0)

__device__ inline half8 p8_of(floatx4 e0, floatx4 e1) {
    half2v a0 = __builtin_bit_cast(half2v,
        __builtin_amdgcn_cvt_pkrtz(EXP2(e0[0]), EXP2(e0[1])));
    half2v a1 = __builtin_bit_cast(half2v,
        __builtin_amdgcn_cvt_pkrtz(EXP2(e0[2]), EXP2(e0[3])));
    half2v a2 = __builtin_bit_cast(half2v,
        __builtin_amdgcn_cvt_pkrtz(EXP2(e1[0]), EXP2(e1[1])));
    half2v a3 = __builtin_bit_cast(half2v,
        __builtin_amdgcn_cvt_pkrtz(EXP2(e1[2]), EXP2(e1[3])));
    half8 p = {a0[0], a0[1], a1[0], a1[1], a2[0], a2[1], a3[0], a3[1]};
    return p;
}

// ---------------------------------------------------------------------------
// K1: QKV projection (unchanged).
// Qf: j-permuted A-layout, log2e-scaled, d>=8 zeroed (denom runs pre-patch).
// Kf: B-layout, d=8,9 = 1.0 (augment channels). Vf: K=32 A-layout f16.
// ---------------------------------------------------------------------------
__global__ __launch_bounds__(256) void qkv_kernel(
    const float* __restrict__ x,
    const float* __restrict__ wq, const float* __restrict__ bq,
    const float* __restrict__ wk, const float* __restrict__ bk,
    const float* __restrict__ wv, const float* __restrict__ bv,
    _Float16* __restrict__ Qf, _Float16* __restrict__ Kf,
    _Float16* __restrict__ Vf)
{
    __shared__ float W[80][64];
    __shared__ float bias[80];
    __shared__ float qs[32][9];
    __shared__ float ks[32][9];
    __shared__ _Float16 vs[32][72];
    const int tid = threadIdx.x;
    for (int idx = tid; idx < 80 * 64; idx += 256) {
        int o = idx >> 6, c = idx & 63;
        float w;
        if (o < 8)       w = wq[o * 64 + c];
        else if (o < 16) w = wk[(o - 8) * 64 + c];
        else             w = wv[(o - 16) * 64 + c];
        W[o][c] = w;
    }
    if (tid < 80) {
        float bb;
        if (tid < 8)       bb = bq[tid];
        else if (tid < 16) bb = bk[tid - 8];
        else               bb = bv[tid - 16];
        bias[tid] = bb;
    }
    __syncthreads();

    const int js = blockIdx.x;          // 0..287
    const int b  = blockIdx.y;
    const int part = tid >> 5;          // 0..7
    const int jl   = tid & 31;
    const int i    = js * 32 + jl;

    float xr[64];
    #pragma unroll
    for (int c = 0; c < 64; ++c)
        xr[c] = x[(size_t)(b * 64 + c) * NPOS + i];

    #pragma unroll
    for (int q = 0; q < 10; ++q) {
        const int o = part * 10 + q;
        float s = bias[o];
        #pragma unroll
        for (int c4 = 0; c4 < 16; ++c4) {
            float4 w4 = *(const float4*)&W[o][c4 * 4];
            s += w4.x * xr[c4*4+0] + w4.y * xr[c4*4+1]
               + w4.z * xr[c4*4+2] + w4.w * xr[c4*4+3];
        }
        if (o < 8)       qs[jl][o] = s;
        else if (o < 16) ks[jl][o - 8] = s;
        else             vs[jl][o - 16] = (_Float16)s;
    }
    __syncthreads();

    const size_t tile = (size_t)b * NST + js;
    {   // Vf
        const int ct = tid >> 6, l = tid & 63;
        const int g = l >> 4, cl = l & 15;
        half8 o8;
        #pragma unroll
        for (int idx = 0; idx < 8; ++idx)
            o8[idx] = vs[8 * g + idx][16 * ct + cl];
        *(half8*)&Vf[(tile * 256 + ct * 64 + l) * 8] = o8;
    }
    if (tid < 128) {   // Qf (j-permuted, log2e-scaled)
        const int l = tid >> 1, e = tid & 1;
        const int m = l & 15, g = l >> 4;
        const int jsrc = 8 * (m >> 2) + 4 * e + (m & 3);
        constexpr float LOG2E = 1.44269504088896f;
        half4 qh;
        #pragma unroll
        for (int r = 0; r < 4; ++r)
            qh[r] = (g < 2) ? (_Float16)(qs[jsrc][4 * g + r] * LOG2E)
                            : (_Float16)0.f;
        ((half4*)Qf)[(tile * 64 + l) * 2 + e] = qh;
    } else {           // Kf (augment dims d=8,9 -> 1.0)
        const int t = tid - 128;
        const int ht = t >> 6, l = t & 63;
        const int il = l & 15, g = l >> 4;
        const int it = js * 2 + ht;
        half4 kh;
        #pragma unroll
        for (int r = 0; r < 4; ++r) {
            if (g < 2)       kh[r] = (_Float16)ks[16 * ht + il][4 * g + r];
            else if (g == 2) kh[r] = (r < 2) ? (_Float16)1.f : (_Float16)0.f;
            else             kh[r] = (_Float16)0.f;
        }
        ((half4*)Kf)[(size_t)(b * NT + it) * 64 + l] = kh;
    }
}

// ---------------------------------------------------------------------------
// K2: denom + patch fused (512 threads, 8 waves; each wave 36 tile-pairs).
// ---------------------------------------------------------------------------
__global__ __launch_bounds__(512, 4) void denom_kernel(
    _Float16* __restrict__ Qf, const _Float16* __restrict__ Kf)
{
    __shared__ float LpS[8][32];
    const int tid = threadIdx.x;
    const int w = tid >> 6, l = tid & 63;   // w = 0..7
    const int js = blockIdx.x;          // 0..287
    const int b  = blockIdx.y;
    const size_t tile = (size_t)b * NST + js;
    const half8* __restrict__ qfb = (const half8*)Qf + (size_t)b * NST * 64;
    const half4* __restrict__ kfb = (const half4*)Kf + (size_t)b * NT * 64;

    half8 qv = qfb[(size_t)js * 64 + l];
    half4 q0 = __builtin_shufflevector(qv, qv, 0, 1, 2, 3);
    half4 q1 = __builtin_shufflevector(qv, qv, 4, 5, 6, 7);

    float sum[2][4];
    #pragma unroll
    for (int e = 0; e < 2; ++e)
        #pragma unroll
        for (int r = 0; r < 4; ++r) sum[e][r] = 0.f;

    const floatx4 z = {0.f, 0.f, 0.f, 0.f};
    #define DACC(E0, E1) do { \
        _Pragma("unroll") \
        for (int r = 0; r < 4; ++r) { \
            sum[0][r] += EXP2(E0[r]); sum[1][r] += EXP2(E1[r]); } \
    } while (0)

    // wave w reads i-tiles w + 8m, m = 0..71 (stride 8 tiles = 512 half4)
    const half4* kp = kfb + (size_t)w * 64 + l;
    half4 kfA = kp[0];
    half4 kfB = kp[512];
    floatx4 eA0 = MFMA16(q0, kfA, z), eA1 = MFMA16(q1, kfA, z);
    floatx4 eB0, eB1;
    for (int k = 0; k < 35; ++k) {
        kfA = kp[(size_t)(2 * k + 2) * 512];
        eB0 = MFMA16(q0, kfB, z); eB1 = MFMA16(q1, kfB, z);
        DACC(eA0, eA1);
        kfB = kp[(size_t)(2 * k + 3) * 512];
        eA0 = MFMA16(q0, kfA, z); eA1 = MFMA16(q1, kfA, z);
        DACC(eB0, eB1);
    }
    eB0 = MFMA16(q0, kfB, z); eB1 = MFMA16(q1, kfB, z);
    DACC(eA0, eA1);
    DACC(eB0, eB1);
    #undef DACC

    #pragma unroll
    for (int e = 0; e < 2; ++e)
        #pragma unroll
        for (int r = 0; r < 4; ++r)
            #pragma unroll
            for (int m = 1; m < 16; m <<= 1)
                sum[e][r] += __shfl_xor(sum[e][r], m, 64);

    if ((l & 15) == 0) {
        const int g = l >> 4;
        #pragma unroll
        for (int e = 0; e < 2; ++e)
            #pragma unroll
            for (int r = 0; r < 4; ++r)
                LpS[w][8 * g + 4 * e + r] = sum[e][r];
    }
    __syncthreads();

    if (tid < 32) {
        float L = 0.f;
        #pragma unroll
        for (int u = 0; u < 8; ++u) L += LpS[u][tid];
        const float v = -__log2f(L);
        _Float16 hi = (_Float16)v;
        _Float16 lo = (_Float16)(v - (float)hi);
        const int m = 4 * (tid >> 3) + (tid & 3);
        const int e = (tid >> 2) & 1;
        half2v hl = {hi, lo};
        ((half2v*)Qf)[((tile * 64 + m + 32) * 2 + e) * 2] = hl;
    }
}

// ---------------------------------------------------------------------------
// K3: attention, 64-i blocks (4 subtiles) x j-split JSPLIT (2 or 4; chosen
// at launch based on ws_size). Grid (288, JSPLIT). Per-subtile LDS combine
// keeps LDS at 17.4 KB so 4 blocks/CU fit at JSPLIT=4 (16 waves/CU).
// Each wave: NST/JSPLIT/4 j-steps of 32 j, depth-1 q/v prefetch.
// Writes f32 partials to part[jh]; combine_kernel sums JSPLIT and adds x.
// ---------------------------------------------------------------------------
template<int JSPLIT>
__global__ __launch_bounds__(256, 4) void attn_kernel(
    const _Float16* __restrict__ Qf, const _Float16* __restrict__ Kf,
    const _Float16* __restrict__ Vf,
    float* __restrict__ part)
{
    constexpr int KSTEPS = NST / JSPLIT / 4;   // 18 (x4) or 36 (x2) per wave
    __shared__ float red[4][64][17];     // 17.4 KB
    const int s   = blockIdx.x;          // 0..287
    const int jh  = blockIdx.y;          // 0..JSPLIT-1
    const int b   = s & 1;
    const int igl = s >> 1;              // 0..143
    const int tid = threadIdx.x;
    const int w = tid >> 6, l = tid & 63;
    const int it0 = igl * 4, i0 = igl * 64;

    const half8* __restrict__ qfb = (const half8*)Qf + (size_t)b * NST * 64;
    const half4* __restrict__ kfb = (const half4*)Kf + (size_t)b * NT * 64;
    const half8* __restrict__ vfb = (const half8*)Vf + (size_t)b * NST * 256;

    half4 kf[4];
    #pragma unroll
    for (int st = 0; st < 4; ++st) kf[st] = kfb[(size_t)(it0 + st) * 64 + l];

    floatx4 acc[4][4];
    #pragma unroll
    for (int st = 0; st < 4; ++st)
        #pragma unroll
        for (int ct = 0; ct < 4; ++ct)
            acc[st][ct] = (floatx4){0.f, 0.f, 0.f, 0.f};

    const floatx4 z = {0.f, 0.f, 0.f, 0.f};

    #define ASTEP(QV, V0, V1, V2, V3) do { \
        half4 qe0 = __builtin_shufflevector(QV, QV, 0, 1, 2, 3); \
        half4 qe1 = __builtin_shufflevector(QV, QV, 4, 5, 6, 7); \
        _Pragma("unroll") \
        for (int st = 0; st < 4; ++st) { \
            floatx4 e0 = MFMA16(qe0, kf[st], z); \
            floatx4 e1 = MFMA16(qe1, kf[st], z); \
            half8 p = p8_of(e0, e1); \
            acc[st][0] = MFMA32(V0, p, acc[st][0]); \
            acc[st][1] = MFMA32(V1, p, acc[st][1]); \
            acc[st][2] = MFMA32(V2, p, acc[st][2]); \
            acc[st][3] = MFMA32(V3, p, acc[st][3]); \
        } \
    } while (0)

    // wave w: j-steps st0 + w + 4k, k = 0..KSTEPS-1 (st0 = jh*NST/JSPLIT)
    const int st0 = jh * (NST / JSPLIT);
    const half8* qpw = qfb + (size_t)(st0 + w) * 64 + l;
    const half8* vpw = vfb + (size_t)(st0 + w) * 256 + l;

    half8 qv = qpw[0];
    half8 v0 = vpw[0], v1 = vpw[64], v2 = vpw[128], v3 = vpw[192];
    for (int k = 0; k < KSTEPS - 1; ++k) {
        const size_t nx = (size_t)(k + 1);
        half8 qn  = qpw[nx * 256];
        half8 v0n = vpw[nx * 1024],       v1n = vpw[nx * 1024 + 64];
        half8 v2n = vpw[nx * 1024 + 128], v3n = vpw[nx * 1024 + 192];
        ASTEP(qv, v0, v1, v2, v3);
        qv = qn; v0 = v0n; v1 = v1n; v2 = v2n; v3 = v3n;
    }
    ASTEP(qv, v0, v1, v2, v3);
    #undef ASTEP

    // Epilogue: per-subtile cross-wave reduction (keeps LDS at 17.4 KB).
    float* __restrict__ P = part + (size_t)jh * ((size_t)BATCH * 64 * NPOS);
    #pragma unroll
    for (int st = 0; st < 4; ++st) {
        __syncthreads();
        #pragma unroll
        for (int ct = 0; ct < 4; ++ct)
            #pragma unroll
            for (int r = 0; r < 4; ++r)
                red[w][l][ct * 4 + r] = acc[st][ct][r];
        __syncthreads();
        // wave w handles c-tile ct == w for this subtile
        const int iq = i0 + 16 * st + (l & 15);
        #pragma unroll
        for (int r = 0; r < 4; ++r) {
            float v = red[0][l][w*4+r] + red[1][l][w*4+r]
                    + red[2][l][w*4+r] + red[3][l][w*4+r];
            int c = 16 * w + 4 * (l >> 4) + r;
            size_t o = ((size_t)(b * 64 + c)) * NPOS + iq;
            P[o] = v;
        }
    }
}

// ---------------------------------------------------------------------------
// K4: combine epilogue — out = gamma * sum(P) + x.
// ---------------------------------------------------------------------------
template<int JSPLIT>
__global__ __launch_bounds__(256) void combine_kernel(
    const float* __restrict__ part, const float* __restrict__ x,
    const float* __restrict__ gamma, float* __restrict__ out)
{
    const float g = gamma[0];
    const size_t idx = (size_t)blockIdx.x * 256 + threadIdx.x; // 0..294911
    const size_t stride = ((size_t)BATCH * 64 * NPOS) / 4;
    const float4* p0 = (const float4*)part;
    float4 a = p0[idx];
    #pragma unroll
    for (int u = 1; u < JSPLIT; ++u) {
        float4 q = p0[idx + (size_t)u * stride];
        a.x += q.x; a.y += q.y; a.z += q.z; a.w += q.w;
    }
    float4 xv = ((const float4*)x)[idx];
    float4 o;
    o.x = g * a.x + xv.x;
    o.y = g * a.y + xv.y;
    o.z = g * a.z + xv.z;
    o.w = g * a.w + xv.w;
    ((float4*)out)[idx] = o;
}

// ---------------------------------------------------------------------------
extern "C" void kernel_launch(void* const* d_in, const int* in_sizes, int n_in,
                              void* d_out, int out_size, void* d_ws, size_t ws_size,
                              hipStream_t stream)
{
    const float* x     = (const float*)d_in[0];
    const float* wq    = (const float*)d_in[1];
    const float* bq    = (const float*)d_in[2];
    const float* wk    = (const float*)d_in[3];
    const float* bk    = (const float*)d_in[4];
    const float* wv    = (const float*)d_in[5];
    const float* bv    = (const float*)d_in[6];
    const float* gamma = (const float*)d_in[7];
    float* out = (float*)d_out;

    char* wsb = (char*)d_ws;
    _Float16* Qf = (_Float16*)wsb;                       //   589,824 B
    _Float16* Kf = (_Float16*)(wsb + 589824);            //   589,824 B
    _Float16* Vf = (_Float16*)(wsb + 1179648);           // 2,359,296 B
    float*    Pp = (float*)(wsb + 3538944);              // JSPLIT x 4,718,592 B

    qkv_kernel<<<dim3(NST, BATCH), 256, 0, stream>>>(
        x, wq, bq, wk, bk, wv, bv, Qf, Kf, Vf);

    denom_kernel<<<dim3(NST, BATCH), 512, 0, stream>>>(Qf, Kf);

    const size_t partBytes = (size_t)BATCH * 64 * NPOS * sizeof(float);
    const size_t need4 = 3538944 + 4 * partBytes;   // 22,413,312 B
    const int nblk = (BATCH * 64 * NPOS / 4) / 256; // 1152

    if (ws_size >= need4) {
        attn_kernel<4><<<dim3(NST, 4), 256, 0, stream>>>(Qf, Kf, Vf, Pp);
        combine_kernel<4><<<nblk, 256, 0, stream>>>(Pp, x, gamma, out);
    } else {
        attn_kernel<2><<<dim3(NST, 2), 256, 0, stream>>>(Qf, Kf, Vf, Pp);
        combine_kernel<2><<<nblk, 256, 0, stream>>>(Pp, x, gamma, out);
    }
}

// Round 4
// 127.065 us; speedup vs baseline: 1.1513x; 1.1513x over previous
//
#include <hip/hip_runtime.h>

using half2v  = __attribute__((ext_vector_type(2))) _Float16;
using half4   = __attribute__((ext_vector_type(4))) _Float16;
using half8   = __attribute__((ext_vector_type(8))) _Float16;
using floatx4 = __attribute__((ext_vector_type(4))) float;

constexpr int BATCH = 2;
constexpr int NPOS  = 96 * 96;    // 9216
constexpr int NT    = NPOS / 16;  // 576 sixteen-wide i-tiles
constexpr int NST   = NPOS / 32;  // 288 thirty-two-wide j-steps

#define EXP2(x) __builtin_amdgcn_exp2f(x)
#define MFMA16(A, B, C) __builtin_amdgcn_mfma_f32_16x16x16f16(A, B, C, 0, 0, 0)
#define MFMA32(A, B, C) __builtin_amdgcn_mfma_f32_16x16x32_f16(A, B, C, 0, 0, 0)

__device__ inline half8 p8_of(floatx4 e0, floatx4 e1) {
    half2v a0 = __builtin_bit_cast(half2v,
        __builtin_amdgcn_cvt_pkrtz(EXP2(e0[0]), EXP2(e0[1])));
    half2v a1 = __builtin_bit_cast(half2v,
        __builtin_amdgcn_cvt_pkrtz(EXP2(e0[2]), EXP2(e0[3])));
    half2v a2 = __builtin_bit_cast(half2v,
        __builtin_amdgcn_cvt_pkrtz(EXP2(e1[0]), EXP2(e1[1])));
    half2v a3 = __builtin_bit_cast(half2v,
        __builtin_amdgcn_cvt_pkrtz(EXP2(e1[2]), EXP2(e1[3])));
    half8 p = {a0[0], a0[1], a1[0], a1[1], a2[0], a2[1], a3[0], a3[1]};
    return p;
}

// ---------------------------------------------------------------------------
// K1: QKV projection (unchanged).
// Qf: j-permuted A-layout, log2e-scaled, d>=8 zeroed (augment dims inert now:
// q_aug = 0 x k_aug = 1 -> contributes 0 to logits; no denom patch anymore).
// Kf: B-layout, d=8,9 = 1.0. Vf: K=32 A-layout f16.
// ---------------------------------------------------------------------------
__global__ __launch_bounds__(256) void qkv_kernel(
    const float* __restrict__ x,
    const float* __restrict__ wq, const float* __restrict__ bq,
    const float* __restrict__ wk, const float* __restrict__ bk,
    const float* __restrict__ wv, const float* __restrict__ bv,
    _Float16* __restrict__ Qf, _Float16* __restrict__ Kf,
    _Float16* __restrict__ Vf)
{
    __shared__ float W[80][64];
    __shared__ float bias[80];
    __shared__ float qs[32][9];
    __shared__ float ks[32][9];
    __shared__ _Float16 vs[32][72];
    const int tid = threadIdx.x;
    for (int idx = tid; idx < 80 * 64; idx += 256) {
        int o = idx >> 6, c = idx & 63;
        float w;
        if (o < 8)       w = wq[o * 64 + c];
        else if (o < 16) w = wk[(o - 8) * 64 + c];
        else             w = wv[(o - 16) * 64 + c];
        W[o][c] = w;
    }
    if (tid < 80) {
        float bb;
        if (tid < 8)       bb = bq[tid];
        else if (tid < 16) bb = bk[tid - 8];
        else               bb = bv[tid - 16];
        bias[tid] = bb;
    }
    __syncthreads();

    const int js = blockIdx.x;          // 0..287
    const int b  = blockIdx.y;
    const int part = tid >> 5;          // 0..7
    const int jl   = tid & 31;
    const int i    = js * 32 + jl;

    float xr[64];
    #pragma unroll
    for (int c = 0; c < 64; ++c)
        xr[c] = x[(size_t)(b * 64 + c) * NPOS + i];

    #pragma unroll
    for (int q = 0; q < 10; ++q) {
        const int o = part * 10 + q;
        float s = bias[o];
        #pragma unroll
        for (int c4 = 0; c4 < 16; ++c4) {
            float4 w4 = *(const float4*)&W[o][c4 * 4];
            s += w4.x * xr[c4*4+0] + w4.y * xr[c4*4+1]
               + w4.z * xr[c4*4+2] + w4.w * xr[c4*4+3];
        }
        if (o < 8)       qs[jl][o] = s;
        else if (o < 16) ks[jl][o - 8] = s;
        else             vs[jl][o - 16] = (_Float16)s;
    }
    __syncthreads();

    const size_t tile = (size_t)b * NST + js;
    {   // Vf
        const int ct = tid >> 6, l = tid & 63;
        const int g = l >> 4, cl = l & 15;
        half8 o8;
        #pragma unroll
        for (int idx = 0; idx < 8; ++idx)
            o8[idx] = vs[8 * g + idx][16 * ct + cl];
        *(half8*)&Vf[(tile * 256 + ct * 64 + l) * 8] = o8;
    }
    if (tid < 128) {   // Qf (j-permuted, log2e-scaled)
        const int l = tid >> 1, e = tid & 1;
        const int m = l & 15, g = l >> 4;
        const int jsrc = 8 * (m >> 2) + 4 * e + (m & 3);
        constexpr float LOG2E = 1.44269504088896f;
        half4 qh;
        #pragma unroll
        for (int r = 0; r < 4; ++r)
            qh[r] = (g < 2) ? (_Float16)(qs[jsrc][4 * g + r] * LOG2E)
                            : (_Float16)0.f;
        ((half4*)Qf)[(tile * 64 + l) * 2 + e] = qh;
    } else {           // Kf (augment dims d=8,9 -> 1.0; inert vs q_aug = 0)
        const int t = tid - 128;
        const int ht = t >> 6, l = t & 63;
        const int il = l & 15, g = l >> 4;
        const int it = js * 2 + ht;
        half4 kh;
        #pragma unroll
        for (int r = 0; r < 4; ++r) {
            if (g < 2)       kh[r] = (_Float16)ks[16 * ht + il][4 * g + r];
            else if (g == 2) kh[r] = (r < 2) ? (_Float16)1.f : (_Float16)0.f;
            else             kh[r] = (_Float16)0.f;
        }
        ((half4*)Kf)[(size_t)(b * NT + it) * 64 + l] = kh;
    }
}

// ---------------------------------------------------------------------------
// K3: attention with FUSED row-sum (denom kernel eliminated).
// 64-i blocks (4 subtiles) x j-split JSPLIT. Grid (288, JSPLIT).
// P = exp2(q.k * log2e) unnormalized (f16); per subtile, one extra
// PV-MFMA against a constant ones-fragment accumulates rowsum[i] = sum_j P.
// launch_bounds(256,2): 256-reg cap -> NO SPILL (round-3 bug: (256,4)
// capped at 128 and spilled the prefetch regs -> 12 MB scratch writes).
// Writes f32 PV partials to part[jh] and rowsum partials to part_rs[jh];
// combine_kernel does out = gamma * sum(PV)/sum(rs) + x.
// ---------------------------------------------------------------------------
template<int JSPLIT>
__global__ __launch_bounds__(256, 2) void attn_kernel(
    const _Float16* __restrict__ Qf, const _Float16* __restrict__ Kf,
    const _Float16* __restrict__ Vf,
    float* __restrict__ part, float* __restrict__ part_rs)
{
    constexpr int KSTEPS = NST / JSPLIT / 4;   // 18 (x4) or 36 (x2) per wave
    __shared__ float red[4][64][17];     // 17.4 KB
    const int s   = blockIdx.x;          // 0..287
    const int jh  = blockIdx.y;          // 0..JSPLIT-1
    const int b   = s & 1;
    const int igl = s >> 1;              // 0..143
    const int tid = threadIdx.x;
    const int w = tid >> 6, l = tid & 63;
    const int it0 = igl * 4, i0 = igl * 64;

    const half8* __restrict__ qfb = (const half8*)Qf + (size_t)b * NST * 64;
    const half4* __restrict__ kfb = (const half4*)Kf + (size_t)b * NT * 64;
    const half8* __restrict__ vfb = (const half8*)Vf + (size_t)b * NST * 256;

    half4 kf[4];
    #pragma unroll
    for (int st = 0; st < 4; ++st) kf[st] = kfb[(size_t)(it0 + st) * 64 + l];

    // ones-fragment: A[m][k] with row m=0 all ones -> D row 0 = column sums
    half8 vones;
    #pragma unroll
    for (int e = 0; e < 8; ++e)
        vones[e] = (_Float16)(((l & 15) == 0) ? 1.f : 0.f);

    floatx4 acc[4][4];
    floatx4 rs[4];
    #pragma unroll
    for (int st = 0; st < 4; ++st) {
        rs[st] = (floatx4){0.f, 0.f, 0.f, 0.f};
        #pragma unroll
        for (int ct = 0; ct < 4; ++ct)
            acc[st][ct] = (floatx4){0.f, 0.f, 0.f, 0.f};
    }

    const floatx4 z = {0.f, 0.f, 0.f, 0.f};

    #define ASTEP(QV, V0, V1, V2, V3) do { \
        half4 qe0 = __builtin_shufflevector(QV, QV, 0, 1, 2, 3); \
        half4 qe1 = __builtin_shufflevector(QV, QV, 4, 5, 6, 7); \
        _Pragma("unroll") \
        for (int st = 0; st < 4; ++st) { \
            floatx4 e0 = MFMA16(qe0, kf[st], z); \
            floatx4 e1 = MFMA16(qe1, kf[st], z); \
            half8 p = p8_of(e0, e1); \
            acc[st][0] = MFMA32(V0, p, acc[st][0]); \
            acc[st][1] = MFMA32(V1, p, acc[st][1]); \
            acc[st][2] = MFMA32(V2, p, acc[st][2]); \
            acc[st][3] = MFMA32(V3, p, acc[st][3]); \
            rs[st]     = MFMA32(vones, p, rs[st]); \
        } \
    } while (0)

    // wave w: j-steps st0 + w + 4k, k = 0..KSTEPS-1 (st0 = jh*NST/JSPLIT)
    const int st0 = jh * (NST / JSPLIT);
    const half8* qpw = qfb + (size_t)(st0 + w) * 64 + l;
    const half8* vpw = vfb + (size_t)(st0 + w) * 256 + l;

    half8 qv = qpw[0];
    half8 v0 = vpw[0], v1 = vpw[64], v2 = vpw[128], v3 = vpw[192];
    for (int k = 0; k < KSTEPS - 1; ++k) {
        const size_t nx = (size_t)(k + 1);
        half8 qn  = qpw[nx * 256];
        half8 v0n = vpw[nx * 1024],       v1n = vpw[nx * 1024 + 64];
        half8 v2n = vpw[nx * 1024 + 128], v3n = vpw[nx * 1024 + 192];
        ASTEP(qv, v0, v1, v2, v3);
        qv = qn; v0 = v0n; v1 = v1n; v2 = v2n; v3 = v3n;
    }
    ASTEP(qv, v0, v1, v2, v3);
    #undef ASTEP

    // Epilogue: per-subtile cross-wave reduction (LDS stays 17.4 KB).
    float* __restrict__ P  = part    + (size_t)jh * ((size_t)BATCH * 64 * NPOS);
    float* __restrict__ Pr = part_rs + (size_t)jh * ((size_t)BATCH * NPOS);
    #pragma unroll
    for (int st = 0; st < 4; ++st) {
        __syncthreads();
        #pragma unroll
        for (int ct = 0; ct < 4; ++ct)
            #pragma unroll
            for (int r = 0; r < 4; ++r)
                red[w][l][ct * 4 + r] = acc[st][ct][r];
        red[w][l][16] = rs[st][0];   // valid (rowsum) for l < 16; 0 rows else
        __syncthreads();
        // wave w handles c-tile ct == w for this subtile
        const int iq = i0 + 16 * st + (l & 15);
        #pragma unroll
        for (int r = 0; r < 4; ++r) {
            float v = red[0][l][w*4+r] + red[1][l][w*4+r]
                    + red[2][l][w*4+r] + red[3][l][w*4+r];
            int c = 16 * w + 4 * (l >> 4) + r;
            size_t o = ((size_t)(b * 64 + c)) * NPOS + iq;
            P[o] = v;
        }
        if (w == 0 && l < 16) {
            float rsv = red[0][l][16] + red[1][l][16]
                      + red[2][l][16] + red[3][l][16];
            Pr[(size_t)b * NPOS + i0 + 16 * st + l] = rsv;
        }
    }
}

// ---------------------------------------------------------------------------
// K4: combine epilogue — out = gamma * sum(PV) / sum(rowsum) + x.
// ---------------------------------------------------------------------------
template<int JSPLIT>
__global__ __launch_bounds__(256) void combine_kernel(
    const float* __restrict__ part, const float* __restrict__ part_rs,
    const float* __restrict__ x, const float* __restrict__ gamma,
    float* __restrict__ out)
{
    const float g = gamma[0];
    const size_t idx = (size_t)blockIdx.x * 256 + threadIdx.x; // 0..73727
    const size_t stride  = ((size_t)BATCH * 64 * NPOS) / 4;    // PV f4/jh
    const size_t rstride = ((size_t)BATCH * NPOS) / 4;         // rs f4/jh
    const int i4 = (int)(idx % (NPOS / 4));
    const int b  = (int)(idx / ((size_t)64 * (NPOS / 4)));
    const float4* p0 = (const float4*)part;
    const float4* r0 = (const float4*)part_rs;

    float4 a = p0[idx];
    float4 rsum = r0[(size_t)b * (NPOS / 4) + i4];
    #pragma unroll
    for (int u = 1; u < JSPLIT; ++u) {
        float4 q = p0[idx + (size_t)u * stride];
        a.x += q.x; a.y += q.y; a.z += q.z; a.w += q.w;
        float4 rq = r0[(size_t)b * (NPOS / 4) + i4 + (size_t)u * rstride];
        rsum.x += rq.x; rsum.y += rq.y; rsum.z += rq.z; rsum.w += rq.w;
    }
    float4 xv = ((const float4*)x)[idx];
    float4 o;
    o.x = g * (a.x / rsum.x) + xv.x;
    o.y = g * (a.y / rsum.y) + xv.y;
    o.z = g * (a.z / rsum.z) + xv.z;
    o.w = g * (a.w / rsum.w) + xv.w;
    ((float4*)out)[idx] = o;
}

// ---------------------------------------------------------------------------
extern "C" void kernel_launch(void* const* d_in, const int* in_sizes, int n_in,
                              void* d_out, int out_size, void* d_ws, size_t ws_size,
                              hipStream_t stream)
{
    const float* x     = (const float*)d_in[0];
    const float* wq    = (const float*)d_in[1];
    const float* bq    = (const float*)d_in[2];
    const float* wk    = (const float*)d_in[3];
    const float* bk    = (const float*)d_in[4];
    const float* wv    = (const float*)d_in[5];
    const float* bv    = (const float*)d_in[6];
    const float* gamma = (const float*)d_in[7];
    float* out = (float*)d_out;

    char* wsb = (char*)d_ws;
    _Float16* Qf = (_Float16*)wsb;                       //   589,824 B
    _Float16* Kf = (_Float16*)(wsb + 589824);            //   589,824 B
    _Float16* Vf = (_Float16*)(wsb + 1179648);           // 2,359,296 B
    float*    Pp = (float*)(wsb + 3538944);              // JSPLIT x 4,718,592 B

    qkv_kernel<<<dim3(NST, BATCH), 256, 0, stream>>>(
        x, wq, bq, wk, bk, wv, bv, Qf, Kf, Vf);

    const size_t partBytes = (size_t)BATCH * 64 * NPOS * sizeof(float);
    const size_t rsBytes   = (size_t)BATCH * NPOS * sizeof(float);
    const size_t need4 = 3538944 + 4 * (partBytes + rsBytes); // 22,708,224 B
    const int nblk = (BATCH * 64 * NPOS / 4) / 256; // 1152

    if (ws_size >= need4) {
        float* Prs = (float*)(wsb + 3538944 + 4 * partBytes);
        attn_kernel<4><<<dim3(NST, 4), 256, 0, stream>>>(Qf, Kf, Vf, Pp, Prs);
        combine_kernel<4><<<nblk, 256, 0, stream>>>(Pp, Prs, x, gamma, out);
    } else {
        float* Prs = (float*)(wsb + 3538944 + 2 * partBytes);
        attn_kernel<2><<<dim3(NST, 2), 256, 0, stream>>>(Qf, Kf, Vf, Pp, Prs);
        combine_kernel<2><<<nblk, 256, 0, stream>>>(Pp, Prs, x, gamma, out);
    }
}

// Round 5
// 123.836 us; speedup vs baseline: 1.1813x; 1.0261x over previous
//
#include <hip/hip_runtime.h>

using half2v  = __attribute__((ext_vector_type(2))) _Float16;
using half4   = __attribute__((ext_vector_type(4))) _Float16;
using half8   = __attribute__((ext_vector_type(8))) _Float16;
using floatx4 = __attribute__((ext_vector_type(4))) float;

constexpr int BATCH = 2;
constexpr int NPOS  = 96 * 96;    // 9216
constexpr int NT    = NPOS / 16;  // 576 sixteen-wide i-tiles
constexpr int NST   = NPOS / 32;  // 288 thirty-two-wide j-steps

#define EXP2(x) __builtin_amdgcn_exp2f(x)
#define MFMA16(A, B, C) __builtin_amdgcn_mfma_f32_16x16x16f16(A, B, C, 0, 0, 0)
#define MFMA32(A, B, C) __builtin_amdgcn_mfma_f32_16x16x32_f16(A, B, C, 0, 0, 0)

__device__ inline half8 p8_of(floatx4 e0, floatx4 e1) {
    half2v a0 = __builtin_bit_cast(half2v,
        __builtin_amdgcn_cvt_pkrtz(EXP2(e0[0]), EXP2(e0[1])));
    half2v a1 = __builtin_bit_cast(half2v,
        __builtin_amdgcn_cvt_pkrtz(EXP2(e0[2]), EXP2(e0[3])));
    half2v a2 = __builtin_bit_cast(half2v,
        __builtin_amdgcn_cvt_pkrtz(EXP2(e1[0]), EXP2(e1[1])));
    half2v a3 = __builtin_bit_cast(half2v,
        __builtin_amdgcn_cvt_pkrtz(EXP2(e1[2]), EXP2(e1[3])));
    half8 p = {a0[0], a0[1], a1[0], a1[1], a2[0], a2[1], a3[0], a3[1]};
    return p;
}

// ---------------------------------------------------------------------------
// K1: QKV projection (unchanged).
// Qf: j-permuted A-layout, log2e-scaled, d>=8 zeroed. Kf: B-layout,
// d=8,9 = 1.0 (inert vs q_aug=0). Vf: K=32 A-layout f16.
// ---------------------------------------------------------------------------
__global__ __launch_bounds__(256) void qkv_kernel(
    const float* __restrict__ x,
    const float* __restrict__ wq, const float* __restrict__ bq,
    const float* __restrict__ wk, const float* __restrict__ bk,
    const float* __restrict__ wv, const float* __restrict__ bv,
    _Float16* __restrict__ Qf, _Float16* __restrict__ Kf,
    _Float16* __restrict__ Vf)
{
    __shared__ float W[80][64];
    __shared__ float bias[80];
    __shared__ float qs[32][9];
    __shared__ float ks[32][9];
    __shared__ _Float16 vs[32][72];
    const int tid = threadIdx.x;
    for (int idx = tid; idx < 80 * 64; idx += 256) {
        int o = idx >> 6, c = idx & 63;
        float w;
        if (o < 8)       w = wq[o * 64 + c];
        else if (o < 16) w = wk[(o - 8) * 64 + c];
        else             w = wv[(o - 16) * 64 + c];
        W[o][c] = w;
    }
    if (tid < 80) {
        float bb;
        if (tid < 8)       bb = bq[tid];
        else if (tid < 16) bb = bk[tid - 8];
        else               bb = bv[tid - 16];
        bias[tid] = bb;
    }
    __syncthreads();

    const int js = blockIdx.x;          // 0..287
    const int b  = blockIdx.y;
    const int part = tid >> 5;          // 0..7
    const int jl   = tid & 31;
    const int i    = js * 32 + jl;

    float xr[64];
    #pragma unroll
    for (int c = 0; c < 64; ++c)
        xr[c] = x[(size_t)(b * 64 + c) * NPOS + i];

    #pragma unroll
    for (int q = 0; q < 10; ++q) {
        const int o = part * 10 + q;
        float s = bias[o];
        #pragma unroll
        for (int c4 = 0; c4 < 16; ++c4) {
            float4 w4 = *(const float4*)&W[o][c4 * 4];
            s += w4.x * xr[c4*4+0] + w4.y * xr[c4*4+1]
               + w4.z * xr[c4*4+2] + w4.w * xr[c4*4+3];
        }
        if (o < 8)       qs[jl][o] = s;
        else if (o < 16) ks[jl][o - 8] = s;
        else             vs[jl][o - 16] = (_Float16)s;
    }
    __syncthreads();

    const size_t tile = (size_t)b * NST + js;
    {   // Vf
        const int ct = tid >> 6, l = tid & 63;
        const int g = l >> 4, cl = l & 15;
        half8 o8;
        #pragma unroll
        for (int idx = 0; idx < 8; ++idx)
            o8[idx] = vs[8 * g + idx][16 * ct + cl];
        *(half8*)&Vf[(tile * 256 + ct * 64 + l) * 8] = o8;
    }
    if (tid < 128) {   // Qf (j-permuted, log2e-scaled)
        const int l = tid >> 1, e = tid & 1;
        const int m = l & 15, g = l >> 4;
        const int jsrc = 8 * (m >> 2) + 4 * e + (m & 3);
        constexpr float LOG2E = 1.44269504088896f;
        half4 qh;
        #pragma unroll
        for (int r = 0; r < 4; ++r)
            qh[r] = (g < 2) ? (_Float16)(qs[jsrc][4 * g + r] * LOG2E)
                            : (_Float16)0.f;
        ((half4*)Qf)[(tile * 64 + l) * 2 + e] = qh;
    } else {           // Kf (augment dims d=8,9 -> 1.0; inert vs q_aug = 0)
        const int t = tid - 128;
        const int ht = t >> 6, l = t & 63;
        const int il = l & 15, g = l >> 4;
        const int it = js * 2 + ht;
        half4 kh;
        #pragma unroll
        for (int r = 0; r < 4; ++r) {
            if (g < 2)       kh[r] = (_Float16)ks[16 * ht + il][4 * g + r];
            else if (g == 2) kh[r] = (r < 2) ? (_Float16)1.f : (_Float16)0.f;
            else             kh[r] = (_Float16)0.f;
        }
        ((half4*)Kf)[(size_t)(b * NT + it) * 64 + l] = kh;
    }
}

// ---------------------------------------------------------------------------
// K3: attention, wave-role split via P-through-LDS (round-5 rewrite).
// Block = 64 i (4 subtiles) x 64 c x j-range; big-steps of 128 j.
// Per big-step: wave w PRODUCES p-fragments for j-substep w (E-MFMA + exp
// + rs) into LDS; one barrier; wave w CONSUMES all 128 j for c-tile w
// (16 independent PV-MFMA32). Breaks the per-wave E->exp->PV serial chain
// across waves (MFMA and VALU pipes fed by different waves/blocks).
// acc is complete per wave -> NO cross-wave PV reduction epilogue.
// LDS: 32KB double-buffered P + 1KB rs-reduce -> 4 blocks/CU; regs ~116.
// ---------------------------------------------------------------------------
template<int JSPLIT>
__global__ __launch_bounds__(256, 3) void attn_kernel(
    const _Float16* __restrict__ Qf, const _Float16* __restrict__ Kf,
    const _Float16* __restrict__ Vf,
    float* __restrict__ part, float* __restrict__ part_rs)
{
    constexpr int NSTEP = NST / JSPLIT / 4;   // big-steps: 18 (x4), 36 (x2)
    __shared__ half8 Pb[2][4][4][64];    // [buf][jsub][subtile][lane] 32 KB
    __shared__ float rsred[4][4][16];    // 1 KB
    const int s   = blockIdx.x;          // 0..287
    const int jh  = blockIdx.y;          // 0..JSPLIT-1
    const int b   = s & 1;
    const int igl = s >> 1;              // 0..143
    const int tid = threadIdx.x;
    const int w = tid >> 6, l = tid & 63;
    const int it0 = igl * 4, i0 = igl * 64;

    const half8* __restrict__ qfb = (const half8*)Qf + (size_t)b * NST * 64;
    const half4* __restrict__ kfb = (const half4*)Kf + (size_t)b * NT * 64;
    const half8* __restrict__ vfb = (const half8*)Vf + (size_t)b * NST * 256;

    half4 kf[4];
    #pragma unroll
    for (int st = 0; st < 4; ++st) kf[st] = kfb[(size_t)(it0 + st) * 64 + l];

    // ones-fragment: A row 0 all ones -> D row 0 = column sums of B
    half8 vones;
    #pragma unroll
    for (int e = 0; e < 8; ++e)
        vones[e] = (_Float16)(((l & 15) == 0) ? 1.f : 0.f);

    floatx4 acc[4];      // PV acc: subtile st, c-tile = w (complete over j)
    floatx4 rs[4];       // rowsum partial for this wave's j-substeps
    #pragma unroll
    for (int st = 0; st < 4; ++st) {
        acc[st] = (floatx4){0.f, 0.f, 0.f, 0.f};
        rs[st]  = (floatx4){0.f, 0.f, 0.f, 0.f};
    }

    const floatx4 z = {0.f, 0.f, 0.f, 0.f};
    const int st0 = jh * (NST / JSPLIT);

    half8 qv = qfb[(size_t)(st0 + w) * 64 + l];

    for (int k = 0; k < NSTEP; ++k) {
        const int t4 = st0 + k * 4;
        const int buf = k & 1;
        // V fragments for the consume phase (c-tile = w), issued early
        half8 v0 = vfb[(size_t)(t4 + 0) * 256 + w * 64 + l];
        half8 v1 = vfb[(size_t)(t4 + 1) * 256 + w * 64 + l];
        half8 v2 = vfb[(size_t)(t4 + 2) * 256 + w * 64 + l];
        half8 v3 = vfb[(size_t)(t4 + 3) * 256 + w * 64 + l];

        // ---- produce: E + exp for j-substep (t4 + w), all 4 subtiles ----
        {
            half4 qe0 = __builtin_shufflevector(qv, qv, 0, 1, 2, 3);
            half4 qe1 = __builtin_shufflevector(qv, qv, 4, 5, 6, 7);
            #pragma unroll
            for (int st = 0; st < 4; ++st) {
                floatx4 e0 = MFMA16(qe0, kf[st], z);
                floatx4 e1 = MFMA16(qe1, kf[st], z);
                half8 p = p8_of(e0, e1);
                rs[st] = MFMA32(vones, p, rs[st]);
                Pb[buf][w][st][l] = p;
            }
        }
        if (k + 1 < NSTEP)
            qv = qfb[(size_t)(st0 + (k + 1) * 4 + w) * 64 + l];

        __syncthreads();

        // ---- consume: PV for c-tile w over all 128 j of this big-step ----
        #pragma unroll
        for (int st = 0; st < 4; ++st) {
            acc[st] = MFMA32(v0, Pb[buf][0][st][l], acc[st]);
            acc[st] = MFMA32(v1, Pb[buf][1][st][l], acc[st]);
            acc[st] = MFMA32(v2, Pb[buf][2][st][l], acc[st]);
            acc[st] = MFMA32(v3, Pb[buf][3][st][l], acc[st]);
        }
        // single barrier per step is safe: consume(k) precedes produce(k+1)
        // in program order, so barrier(k+1) orders all consume(k) before
        // any produce(k+2) reuses this buffer.
    }

    // ---- PV store: acc is complete (summed over all block j-range) ----
    float* __restrict__ P  = part    + (size_t)jh * ((size_t)BATCH * 64 * NPOS);
    float* __restrict__ Pr = part_rs + (size_t)jh * ((size_t)BATCH * NPOS);
    {
        const int iq = i0 + (l & 15);
        #pragma unroll
        for (int st = 0; st < 4; ++st)
            #pragma unroll
            for (int r = 0; r < 4; ++r) {
                int c = 16 * w + 4 * (l >> 4) + r;
                size_t o = ((size_t)(b * 64 + c)) * NPOS + iq + 16 * st;
                P[o] = acc[st][r];
            }
    }

    // ---- rowsum: cross-wave sum (each wave covered 1/4 of block's j) ----
    if (l < 16) {
        #pragma unroll
        for (int st = 0; st < 4; ++st) rsred[w][st][l] = rs[st][0];
    }
    __syncthreads();
    if (w == 0 && l < 16) {
        #pragma unroll
        for (int st = 0; st < 4; ++st) {
            float rsv = rsred[0][st][l] + rsred[1][st][l]
                      + rsred[2][st][l] + rsred[3][st][l];
            Pr[(size_t)b * NPOS + i0 + 16 * st + l] = rsv;
        }
    }
}

// ---------------------------------------------------------------------------
// K4: combine epilogue — out = gamma * sum(PV) / sum(rowsum) + x.
// ---------------------------------------------------------------------------
template<int JSPLIT>
__global__ __launch_bounds__(256) void combine_kernel(
    const float* __restrict__ part, const float* __restrict__ part_rs,
    const float* __restrict__ x, const float* __restrict__ gamma,
    float* __restrict__ out)
{
    const float g = gamma[0];
    const size_t idx = (size_t)blockIdx.x * 256 + threadIdx.x; // 0..73727
    const size_t stride  = ((size_t)BATCH * 64 * NPOS) / 4;    // PV f4/jh
    const size_t rstride = ((size_t)BATCH * NPOS) / 4;         // rs f4/jh
    const int i4 = (int)(idx % (NPOS / 4));
    const int b  = (int)(idx / ((size_t)64 * (NPOS / 4)));
    const float4* p0 = (const float4*)part;
    const float4* r0 = (const float4*)part_rs;

    float4 a = p0[idx];
    float4 rsum = r0[(size_t)b * (NPOS / 4) + i4];
    #pragma unroll
    for (int u = 1; u < JSPLIT; ++u) {
        float4 q = p0[idx + (size_t)u * stride];
        a.x += q.x; a.y += q.y; a.z += q.z; a.w += q.w;
        float4 rq = r0[(size_t)b * (NPOS / 4) + i4 + (size_t)u * rstride];
        rsum.x += rq.x; rsum.y += rq.y; rsum.z += rq.z; rsum.w += rq.w;
    }
    float4 xv = ((const float4*)x)[idx];
    float4 o;
    o.x = g * (a.x / rsum.x) + xv.x;
    o.y = g * (a.y / rsum.y) + xv.y;
    o.z = g * (a.z / rsum.z) + xv.z;
    o.w = g * (a.w / rsum.w) + xv.w;
    ((float4*)out)[idx] = o;
}

// ---------------------------------------------------------------------------
extern "C" void kernel_launch(void* const* d_in, const int* in_sizes, int n_in,
                              void* d_out, int out_size, void* d_ws, size_t ws_size,
                              hipStream_t stream)
{
    const float* x     = (const float*)d_in[0];
    const float* wq    = (const float*)d_in[1];
    const float* bq    = (const float*)d_in[2];
    const float* wk    = (const float*)d_in[3];
    const float* bk    = (const float*)d_in[4];
    const float* wv    = (const float*)d_in[5];
    const float* bv    = (const float*)d_in[6];
    const float* gamma = (const float*)d_in[7];
    float* out = (float*)d_out;

    char* wsb = (char*)d_ws;
    _Float16* Qf = (_Float16*)wsb;                       //   589,824 B
    _Float16* Kf = (_Float16*)(wsb + 589824);            //   589,824 B
    _Float16* Vf = (_Float16*)(wsb + 1179648);           // 2,359,296 B
    float*    Pp = (float*)(wsb + 3538944);              // JSPLIT x 4,718,592 B

    qkv_kernel<<<dim3(NST, BATCH), 256, 0, stream>>>(
        x, wq, bq, wk, bk, wv, bv, Qf, Kf, Vf);

    const size_t partBytes = (size_t)BATCH * 64 * NPOS * sizeof(float);
    const size_t rsBytes   = (size_t)BATCH * NPOS * sizeof(float);
    const size_t need4 = 3538944 + 4 * (partBytes + rsBytes); // 22,708,224 B
    const int nblk = (BATCH * 64 * NPOS / 4) / 256; // 1152

    if (ws_size >= need4) {
        float* Prs = (float*)(wsb + 3538944 + 4 * partBytes);
        attn_kernel<4><<<dim3(NST, 4), 256, 0, stream>>>(Qf, Kf, Vf, Pp, Prs);
        combine_kernel<4><<<nblk, 256, 0, stream>>>(Pp, Prs, x, gamma, out);
    } else {
        float* Prs = (float*)(wsb + 3538944 + 2 * partBytes);
        attn_kernel<2><<<dim3(NST, 2), 256, 0, stream>>>(Qf, Kf, Vf, Pp, Prs);
        combine_kernel<2><<<nblk, 256, 0, stream>>>(Pp, Prs, x, gamma, out);
    }
}

// Round 6
// 122.706 us; speedup vs baseline: 1.1922x; 1.0092x over previous
//
#include <hip/hip_runtime.h>

using half2v  = __attribute__((ext_vector_type(2))) _Float16;
using half4   = __attribute__((ext_vector_type(4))) _Float16;
using half8   = __attribute__((ext_vector_type(8))) _Float16;
using floatx4 = __attribute__((ext_vector_type(4))) float;

constexpr int BATCH = 2;
constexpr int NPOS  = 96 * 96;    // 9216
constexpr int NT    = NPOS / 16;  // 576 sixteen-wide i-tiles
constexpr int NST   = NPOS / 32;  // 288 thirty-two-wide j-steps

#define EXP2(x) __builtin_amdgcn_exp2f(x)
#define MFMA16(A, B, C) __builtin_amdgcn_mfma_f32_16x16x16f16(A, B, C, 0, 0, 0)
#define MFMA32(A, B, C) __builtin_amdgcn_mfma_f32_16x16x32_f16(A, B, C, 0, 0, 0)

__device__ inline half8 p8_of(floatx4 e0, floatx4 e1) {
    half2v a0 = __builtin_bit_cast(half2v,
        __builtin_amdgcn_cvt_pkrtz(EXP2(e0[0]), EXP2(e0[1])));
    half2v a1 = __builtin_bit_cast(half2v,
        __builtin_amdgcn_cvt_pkrtz(EXP2(e0[2]), EXP2(e0[3])));
    half2v a2 = __builtin_bit_cast(half2v,
        __builtin_amdgcn_cvt_pkrtz(EXP2(e1[0]), EXP2(e1[1])));
    half2v a3 = __builtin_bit_cast(half2v,
        __builtin_amdgcn_cvt_pkrtz(EXP2(e1[2]), EXP2(e1[3])));
    half8 p = {a0[0], a0[1], a1[0], a1[1], a2[0], a2[1], a3[0], a3[1]};
    return p;
}

// ---------------------------------------------------------------------------
// K1: QKV projection (unchanged).
// Qf: j-permuted A-layout, log2e-scaled, d>=8 zeroed. Kf: B-layout,
// d=8,9 = 1.0 (inert vs q_aug=0). Vf: K=32 A-layout f16.
// ---------------------------------------------------------------------------
__global__ __launch_bounds__(256) void qkv_kernel(
    const float* __restrict__ x,
    const float* __restrict__ wq, const float* __restrict__ bq,
    const float* __restrict__ wk, const float* __restrict__ bk,
    const float* __restrict__ wv, const float* __restrict__ bv,
    _Float16* __restrict__ Qf, _Float16* __restrict__ Kf,
    _Float16* __restrict__ Vf)
{
    __shared__ float W[80][64];
    __shared__ float bias[80];
    __shared__ float qs[32][9];
    __shared__ float ks[32][9];
    __shared__ _Float16 vs[32][72];
    const int tid = threadIdx.x;
    for (int idx = tid; idx < 80 * 64; idx += 256) {
        int o = idx >> 6, c = idx & 63;
        float w;
        if (o < 8)       w = wq[o * 64 + c];
        else if (o < 16) w = wk[(o - 8) * 64 + c];
        else             w = wv[(o - 16) * 64 + c];
        W[o][c] = w;
    }
    if (tid < 80) {
        float bb;
        if (tid < 8)       bb = bq[tid];
        else if (tid < 16) bb = bk[tid - 8];
        else               bb = bv[tid - 16];
        bias[tid] = bb;
    }
    __syncthreads();

    const int js = blockIdx.x;          // 0..287
    const int b  = blockIdx.y;
    const int part = tid >> 5;          // 0..7
    const int jl   = tid & 31;
    const int i    = js * 32 + jl;

    float xr[64];
    #pragma unroll
    for (int c = 0; c < 64; ++c)
        xr[c] = x[(size_t)(b * 64 + c) * NPOS + i];

    #pragma unroll
    for (int q = 0; q < 10; ++q) {
        const int o = part * 10 + q;
        float s = bias[o];
        #pragma unroll
        for (int c4 = 0; c4 < 16; ++c4) {
            float4 w4 = *(const float4*)&W[o][c4 * 4];
            s += w4.x * xr[c4*4+0] + w4.y * xr[c4*4+1]
               + w4.z * xr[c4*4+2] + w4.w * xr[c4*4+3];
        }
        if (o < 8)       qs[jl][o] = s;
        else if (o < 16) ks[jl][o - 8] = s;
        else             vs[jl][o - 16] = (_Float16)s;
    }
    __syncthreads();

    const size_t tile = (size_t)b * NST + js;
    {   // Vf
        const int ct = tid >> 6, l = tid & 63;
        const int g = l >> 4, cl = l & 15;
        half8 o8;
        #pragma unroll
        for (int idx = 0; idx < 8; ++idx)
            o8[idx] = vs[8 * g + idx][16 * ct + cl];
        *(half8*)&Vf[(tile * 256 + ct * 64 + l) * 8] = o8;
    }
    if (tid < 128) {   // Qf (j-permuted, log2e-scaled)
        const int l = tid >> 1, e = tid & 1;
        const int m = l & 15, g = l >> 4;
        const int jsrc = 8 * (m >> 2) + 4 * e + (m & 3);
        constexpr float LOG2E = 1.44269504088896f;
        half4 qh;
        #pragma unroll
        for (int r = 0; r < 4; ++r)
            qh[r] = (g < 2) ? (_Float16)(qs[jsrc][4 * g + r] * LOG2E)
                            : (_Float16)0.f;
        ((half4*)Qf)[(tile * 64 + l) * 2 + e] = qh;
    } else {           // Kf (augment dims d=8,9 -> 1.0; inert vs q_aug = 0)
        const int t = tid - 128;
        const int ht = t >> 6, l = t & 63;
        const int il = l & 15, g = l >> 4;
        const int it = js * 2 + ht;
        half4 kh;
        #pragma unroll
        for (int r = 0; r < 4; ++r) {
            if (g < 2)       kh[r] = (_Float16)ks[16 * ht + il][4 * g + r];
            else if (g == 2) kh[r] = (r < 2) ? (_Float16)1.f : (_Float16)0.f;
            else             kh[r] = (_Float16)0.f;
        }
        ((half4*)Kf)[(size_t)(b * NT + it) * 64 + l] = kh;
    }
}

// ---------------------------------------------------------------------------
// K3: attention, round-6: SOFTWARE-PIPELINED produce/consume.
// Iteration k body = produce(k+1) [E-MFMA + exp + pkrtz + LDS write, VALU-
// heavy] merged with consume(k) [16 PV-MFMA32 from LDS, MFMA-heavy]. The two
// halves have no data deps -> scheduler interleaves, filling BOTH pipes from
// one wave (round-5 phase-lock paid sum of phases, not max). One barrier per
// iteration: separates produce(k+1) writes from consume(k+1) reads, and
// consume(k) reads from produce(k+2) overwrite (double buffer).
// ---------------------------------------------------------------------------
template<int JSPLIT>
__global__ __launch_bounds__(256, 3) void attn_kernel(
    const _Float16* __restrict__ Qf, const _Float16* __restrict__ Kf,
    const _Float16* __restrict__ Vf,
    float* __restrict__ part, float* __restrict__ part_rs)
{
    constexpr int NSTEP = NST / JSPLIT / 4;   // big-steps: 18 (x4), 36 (x2)
    __shared__ half8 Pb[2][4][4][64];    // [buf][jsub][subtile][lane] 32 KB
    __shared__ float rsred[4][4][16];    // 1 KB
    const int s   = blockIdx.x;          // 0..287
    const int jh  = blockIdx.y;          // 0..JSPLIT-1
    const int b   = s & 1;
    const int igl = s >> 1;              // 0..143
    const int tid = threadIdx.x;
    const int w = tid >> 6, l = tid & 63;
    const int it0 = igl * 4, i0 = igl * 64;

    const half8* __restrict__ qfb = (const half8*)Qf + (size_t)b * NST * 64;
    const half4* __restrict__ kfb = (const half4*)Kf + (size_t)b * NT * 64;
    const half8* __restrict__ vfb = (const half8*)Vf + (size_t)b * NST * 256;

    half4 kf[4];
    #pragma unroll
    for (int st = 0; st < 4; ++st) kf[st] = kfb[(size_t)(it0 + st) * 64 + l];

    // ones-fragment: A row 0 all ones -> D row 0 = column sums of B
    half8 vones;
    #pragma unroll
    for (int e = 0; e < 8; ++e)
        vones[e] = (_Float16)(((l & 15) == 0) ? 1.f : 0.f);

    floatx4 acc[4];      // PV acc: subtile st, c-tile = w (complete over j)
    floatx4 rs[4];       // rowsum partial for this wave's j-substeps
    #pragma unroll
    for (int st = 0; st < 4; ++st) {
        acc[st] = (floatx4){0.f, 0.f, 0.f, 0.f};
        rs[st]  = (floatx4){0.f, 0.f, 0.f, 0.f};
    }

    const floatx4 z = {0.f, 0.f, 0.f, 0.f};
    const int st0 = jh * (NST / JSPLIT);

    // produce step k writes Pb[k&1]; consume step k reads Pb[k&1].
    #define PRODUCE(QV, BUF) do { \
        half4 qe0 = __builtin_shufflevector(QV, QV, 0, 1, 2, 3); \
        half4 qe1 = __builtin_shufflevector(QV, QV, 4, 5, 6, 7); \
        _Pragma("unroll") \
        for (int st = 0; st < 4; ++st) { \
            floatx4 e0 = MFMA16(qe0, kf[st], z); \
            floatx4 e1 = MFMA16(qe1, kf[st], z); \
            half8 pw = p8_of(e0, e1); \
            rs[st] = MFMA32(vones, pw, rs[st]); \
            Pb[BUF][w][st][l] = pw; \
        } \
    } while (0)

    // ---- prologue: produce(0); prefetch q(1), v(0) ----
    half8 qv = qfb[(size_t)(st0 + w) * 64 + l];
    half8 v0 = vfb[(size_t)(st0 + 0) * 256 + w * 64 + l];
    half8 v1 = vfb[(size_t)(st0 + 1) * 256 + w * 64 + l];
    half8 v2 = vfb[(size_t)(st0 + 2) * 256 + w * 64 + l];
    half8 v3 = vfb[(size_t)(st0 + 3) * 256 + w * 64 + l];
    PRODUCE(qv, 0);
    qv = qfb[(size_t)(st0 + 4 + w) * 64 + l];     // q(1) (NSTEP >= 2)
    __syncthreads();

    for (int k = 0; k < NSTEP - 1; ++k) {
        const int b0 = k & 1, b1 = b0 ^ 1;
        const int t4n = st0 + (k + 1) * 4;
        // prefetch v(k+1) and q(min(k+2, last)) — issued first
        half8 v0n = vfb[(size_t)(t4n + 0) * 256 + w * 64 + l];
        half8 v1n = vfb[(size_t)(t4n + 1) * 256 + w * 64 + l];
        half8 v2n = vfb[(size_t)(t4n + 2) * 256 + w * 64 + l];
        half8 v3n = vfb[(size_t)(t4n + 3) * 256 + w * 64 + l];
        const int kq = (k + 2 < NSTEP) ? (k + 2) : (NSTEP - 1);
        half8 qn = qfb[(size_t)(st0 + kq * 4 + w) * 64 + l];

        // merged per-subtile: consume-reads + produce(k+1) + consume-MFMAs.
        // The exp chain (produce) and the PV MFMAs (consume) are independent.
        {
            half4 qe0 = __builtin_shufflevector(qv, qv, 0, 1, 2, 3);
            half4 qe1 = __builtin_shufflevector(qv, qv, 4, 5, 6, 7);
            #pragma unroll
            for (int st = 0; st < 4; ++st) {
                half8 p0 = Pb[b0][0][st][l];
                half8 p1 = Pb[b0][1][st][l];
                half8 p2 = Pb[b0][2][st][l];
                half8 p3 = Pb[b0][3][st][l];
                floatx4 e0 = MFMA16(qe0, kf[st], z);
                floatx4 e1 = MFMA16(qe1, kf[st], z);
                half8 pw = p8_of(e0, e1);
                rs[st] = MFMA32(vones, pw, rs[st]);
                Pb[b1][w][st][l] = pw;
                acc[st] = MFMA32(v0, p0, acc[st]);
                acc[st] = MFMA32(v1, p1, acc[st]);
                acc[st] = MFMA32(v2, p2, acc[st]);
                acc[st] = MFMA32(v3, p3, acc[st]);
            }
        }
        v0 = v0n; v1 = v1n; v2 = v2n; v3 = v3n; qv = qn;
        __syncthreads();
    }

    // ---- epilogue: consume(NSTEP-1) ----
    {
        const int b0 = (NSTEP - 1) & 1;
        #pragma unroll
        for (int st = 0; st < 4; ++st) {
            acc[st] = MFMA32(v0, Pb[b0][0][st][l], acc[st]);
            acc[st] = MFMA32(v1, Pb[b0][1][st][l], acc[st]);
            acc[st] = MFMA32(v2, Pb[b0][2][st][l], acc[st]);
            acc[st] = MFMA32(v3, Pb[b0][3][st][l], acc[st]);
        }
    }
    #undef PRODUCE

    // ---- PV store: acc is complete (summed over all block j-range) ----
    float* __restrict__ P  = part    + (size_t)jh * ((size_t)BATCH * 64 * NPOS);
    float* __restrict__ Pr = part_rs + (size_t)jh * ((size_t)BATCH * NPOS);
    {
        const int iq = i0 + (l & 15);
        #pragma unroll
        for (int st = 0; st < 4; ++st)
            #pragma unroll
            for (int r = 0; r < 4; ++r) {
                int c = 16 * w + 4 * (l >> 4) + r;
                size_t o = ((size_t)(b * 64 + c)) * NPOS + iq + 16 * st;
                P[o] = acc[st][r];
            }
    }

    // ---- rowsum: cross-wave sum (each wave covered 1/4 of block's j) ----
    if (l < 16) {
        #pragma unroll
        for (int st = 0; st < 4; ++st) rsred[w][st][l] = rs[st][0];
    }
    __syncthreads();
    if (w == 0 && l < 16) {
        #pragma unroll
        for (int st = 0; st < 4; ++st) {
            float rsv = rsred[0][st][l] + rsred[1][st][l]
                      + rsred[2][st][l] + rsred[3][st][l];
            Pr[(size_t)b * NPOS + i0 + 16 * st + l] = rsv;
        }
    }
}

// ---------------------------------------------------------------------------
// K4: combine epilogue — out = gamma * sum(PV) / sum(rowsum) + x.
// ---------------------------------------------------------------------------
template<int JSPLIT>
__global__ __launch_bounds__(256) void combine_kernel(
    const float* __restrict__ part, const float* __restrict__ part_rs,
    const float* __restrict__ x, const float* __restrict__ gamma,
    float* __restrict__ out)
{
    const float g = gamma[0];
    const size_t idx = (size_t)blockIdx.x * 256 + threadIdx.x; // 0..73727
    const size_t stride  = ((size_t)BATCH * 64 * NPOS) / 4;    // PV f4/jh
    const size_t rstride = ((size_t)BATCH * NPOS) / 4;         // rs f4/jh
    const int i4 = (int)(idx % (NPOS / 4));
    const int b  = (int)(idx / ((size_t)64 * (NPOS / 4)));
    const float4* p0 = (const float4*)part;
    const float4* r0 = (const float4*)part_rs;

    float4 a = p0[idx];
    float4 rsum = r0[(size_t)b * (NPOS / 4) + i4];
    #pragma unroll
    for (int u = 1; u < JSPLIT; ++u) {
        float4 q = p0[idx + (size_t)u * stride];
        a.x += q.x; a.y += q.y; a.z += q.z; a.w += q.w;
        float4 rq = r0[(size_t)b * (NPOS / 4) + i4 + (size_t)u * rstride];
        rsum.x += rq.x; rsum.y += rq.y; rsum.z += rq.z; rsum.w += rq.w;
    }
    float4 xv = ((const float4*)x)[idx];
    float4 o;
    o.x = g * (a.x / rsum.x) + xv.x;
    o.y = g * (a.y / rsum.y) + xv.y;
    o.z = g * (a.z / rsum.z) + xv.z;
    o.w = g * (a.w / rsum.w) + xv.w;
    ((float4*)out)[idx] = o;
}

// ---------------------------------------------------------------------------
extern "C" void kernel_launch(void* const* d_in, const int* in_sizes, int n_in,
                              void* d_out, int out_size, void* d_ws, size_t ws_size,
                              hipStream_t stream)
{
    const float* x     = (const float*)d_in[0];
    const float* wq    = (const float*)d_in[1];
    const float* bq    = (const float*)d_in[2];
    const float* wk    = (const float*)d_in[3];
    const float* bk    = (const float*)d_in[4];
    const float* wv    = (const float*)d_in[5];
    const float* bv    = (const float*)d_in[6];
    const float* gamma = (const float*)d_in[7];
    float* out = (float*)d_out;

    char* wsb = (char*)d_ws;
    _Float16* Qf = (_Float16*)wsb;                       //   589,824 B
    _Float16* Kf = (_Float16*)(wsb + 589824);            //   589,824 B
    _Float16* Vf = (_Float16*)(wsb + 1179648);           // 2,359,296 B
    float*    Pp = (float*)(wsb + 3538944);              // JSPLIT x 4,718,592 B

    qkv_kernel<<<dim3(NST, BATCH), 256, 0, stream>>>(
        x, wq, bq, wk, bk, wv, bv, Qf, Kf, Vf);

    const size_t partBytes = (size_t)BATCH * 64 * NPOS * sizeof(float);
    const size_t rsBytes   = (size_t)BATCH * NPOS * sizeof(float);
    const size_t need4 = 3538944 + 4 * (partBytes + rsBytes); // 22,708,224 B
    const int nblk = (BATCH * 64 * NPOS / 4) / 256; // 1152

    if (ws_size >= need4) {
        float* Prs = (float*)(wsb + 3538944 + 4 * partBytes);
        attn_kernel<4><<<dim3(NST, 4), 256, 0, stream>>>(Qf, Kf, Vf, Pp, Prs);
        combine_kernel<4><<<nblk, 256, 0, stream>>>(Pp, Prs, x, gamma, out);
    } else {
        float* Prs = (float*)(wsb + 3538944 + 2 * partBytes);
        attn_kernel<2><<<dim3(NST, 2), 256, 0, stream>>>(Qf, Kf, Vf, Pp, Prs);
        combine_kernel<2><<<nblk, 256, 0, stream>>>(Pp, Prs, x, gamma, out);
    }
}